// Round 5
// baseline (445.374 us; speedup 1.0000x reference)
//
#include <hip/hip_runtime.h>
#include <hip/hip_bf16.h>

#define N_NODES 50000
#define N_EDGES 800000
#define IN_F 128
#define OUT_F 128
#define TOPK 32

typedef __attribute__((ext_vector_type(8))) short short8;
typedef __attribute__((ext_vector_type(4))) float f32x4;

static __device__ inline unsigned short f2bf(float x) {
    __hip_bfloat16 h = __float2bfloat16(x);
    return *reinterpret_cast<unsigned short*>(&h);
}

// ---------------------------------------------------------------------------
// Kernel 1: fused in-degree count + dedup mask + payload pack.
// packed[node][k] = (bf16(val if slot wins else 0) << 16) | idx
// Dead slots carry value 0 so the agg kernel needs no mask load.
// ---------------------------------------------------------------------------
__global__ void deg_mask_pack_kernel(const int* __restrict__ dst, int* __restrict__ deg,
                                     const float* __restrict__ vals,
                                     const int* __restrict__ topk_idx,
                                     unsigned* __restrict__ packed, int E, int n) {
    int t = blockIdx.x * blockDim.x + threadIdx.x;
    if (t < E) atomicAdd(&deg[dst[t]], 1);
    if (t < n) {
        int idx[TOPK];
        float v[TOPK];
#pragma unroll
        for (int k = 0; k < TOPK; k += 4) {
            *(int4*)&idx[k] = *(const int4*)&topk_idx[t * TOPK + k];
            *(float4*)&v[k] = *(const float4*)&vals[t * TOPK + k];
        }
        unsigned o[TOPK];
#pragma unroll
        for (int k = 0; k < TOPK; ++k) {
            bool win = true;
            for (int j = k + 1; j < TOPK; ++j)
                if (idx[j] == idx[k]) { win = false; break; }
            float vv = win ? v[k] : 0.f;
            o[k] = ((unsigned)f2bf(vv) << 16) | (unsigned)(idx[k] & 0xffff);
        }
#pragma unroll
        for (int k = 0; k < TOPK; k += 4)
            *(uint4*)&packed[t * TOPK + k] = *(const uint4*)&o[k];
    }
}

// ---------------------------------------------------------------------------
// Kernel 2: single-block exclusive scan of deg -> off[0..n]
// ---------------------------------------------------------------------------
__global__ __launch_bounds__(1024) void scan_kernel(const int* __restrict__ deg,
                                                    int* __restrict__ off, int n) {
    __shared__ int partial[1024];
    int t = threadIdx.x;
    int chunk = (n + 1023) / 1024;
    int start = t * chunk;
    int end = min(start + chunk, n);
    int s = 0;
    for (int i = start; i < end; ++i) s += deg[i];
    partial[t] = s;
    __syncthreads();
    for (int d = 1; d < 1024; d <<= 1) {
        int v = (t >= d) ? partial[t - d] : 0;
        __syncthreads();
        partial[t] += v;
        __syncthreads();
    }
    int run = (t > 0) ? partial[t - 1] : 0;
    for (int i = start; i < end; ++i) { off[i] = run; run += deg[i]; }
    if (t == 1023) off[n] = run;
}

// ---------------------------------------------------------------------------
// Kernel 3: CSR scatter — esrc[off[d] + cursor[d]++] = src[e]
// ---------------------------------------------------------------------------
__global__ void csr_scatter_kernel(const int* __restrict__ src, const int* __restrict__ dst,
                                   const int* __restrict__ off, int* __restrict__ cursor,
                                   int* __restrict__ esrc, int E) {
    int e = blockIdx.x * blockDim.x + threadIdx.x;
    if (e >= E) return;
    int d = dst[e];
    int pos = off[d] + atomicAdd(&cursor[d], 1);
    esrc[pos] = src[e];
}

// ---------------------------------------------------------------------------
// Kernel 4: aggregation over packed payload. One wave per dst node.
// 16 lanes per edge (uint2 = 2 slots/lane) -> 4 edges per iteration,
// unrolled x2 -> 8 edges in flight. Branchless tail: clamped edge index +
// zero multiplier keeps all loads unconditional so they software-pipeline.
// ---------------------------------------------------------------------------
__global__ __launch_bounds__(64) void agg_packed_kernel(
    const int* __restrict__ off, const int* __restrict__ esrc,
    const uint2* __restrict__ packed,  // [N][16] uint2 view
    unsigned short* __restrict__ agg_bf, int n) {
    __shared__ float acc[IN_F];
    int d = blockIdx.x;
    int l = threadIdx.x;
    acc[l] = 0.f;
    acc[l + 64] = 0.f;
    __syncthreads();
    int b = off[d], e = off[d + 1];
    int g = l >> 4, sl = l & 15;
    for (int j = b; j < e; j += 8) {
        int ja = j + g, jb = j + 4 + g;
        int j0 = min(ja, e - 1), j1 = min(jb, e - 1);
        int s0 = esrc[j0], s1 = esrc[j1];
        uint2 p0 = packed[s0 * 16 + sl];
        uint2 p1 = packed[s1 * 16 + sl];
        float m0 = (ja < e) ? 1.f : 0.f;
        float m1 = (jb < e) ? 1.f : 0.f;
        float v0x = __uint_as_float(p0.x & 0xffff0000u) * m0;
        float v0y = __uint_as_float(p0.y & 0xffff0000u) * m0;
        float v1x = __uint_as_float(p1.x & 0xffff0000u) * m1;
        float v1y = __uint_as_float(p1.y & 0xffff0000u) * m1;
        atomicAdd(&acc[p0.x & 127], v0x);
        atomicAdd(&acc[p0.y & 127], v0y);
        atomicAdd(&acc[p1.x & 127], v1x);
        atomicAdd(&acc[p1.y & 127], v1y);
    }
    __syncthreads();
    float inv = 1.0f / (float)max(e - b, 1);
    __hip_bfloat162 h;
    h.x = __float2bfloat16(acc[2 * l] * inv);
    h.y = __float2bfloat16(acc[2 * l + 1] * inv);
    *(__hip_bfloat162*)&agg_bf[d * IN_F + 2 * l] = h;
}

// ---------------------------------------------------------------------------
// Kernel 5: fused MFMA GEMM:  out = [feat | agg] @ [Ws ; Wn] + b
// M=50000, N=128, K=256, bf16 MFMA 16x16x32. (unchanged from round 4)
// ---------------------------------------------------------------------------
#define BK_PAD 264
__global__ __launch_bounds__(256, 2) void fused_gemm_kernel(
    const float* __restrict__ feat, const unsigned short* __restrict__ agg_bf,
    const float* __restrict__ Ws, const float* __restrict__ Wn,
    const float* __restrict__ bias, float* __restrict__ out, int n) {
    __shared__ unsigned short BL[OUT_F * BK_PAD];  // 67.5 KB

    int t = threadIdx.x;
    {
        int col = t & 127;
        int khalf = t >> 7;  // 0: Ws (k<128), 1: Wn (k>=128)
        const float* W = khalf ? Wn : Ws;
        unsigned short* dstp = &BL[col * BK_PAD + khalf * 128];
#pragma unroll 4
        for (int kk = 0; kk < 128; kk += 2) {
            float w0 = W[kk * OUT_F + col];
            float w1 = W[(kk + 1) * OUT_F + col];
            unsigned v = (unsigned)f2bf(w0) | ((unsigned)f2bf(w1) << 16);
            *(unsigned*)&dstp[kk] = v;
        }
    }
    __syncthreads();

    int wave = t >> 6;
    int lane = t & 63;
    int quad = lane >> 4;
    int lq = lane & 15;
    int rowbase = blockIdx.x * 128 + wave * 32;
    int r0 = rowbase + lq;
    int r1 = rowbase + 16 + lq;

    f32x4 acc0[8], acc1[8];
#pragma unroll
    for (int i = 0; i < 8; ++i) { acc0[i] = (f32x4){0,0,0,0}; acc1[i] = (f32x4){0,0,0,0}; }

#pragma unroll
    for (int ks = 0; ks < 8; ++ks) {
        int k0 = ks * 32 + quad * 8;
        short8 a0, a1;
        if (ks < 4) {
            float4 z = {0.f, 0.f, 0.f, 0.f};
            float4 f00 = (r0 < n) ? *(const float4*)&feat[r0 * IN_F + k0] : z;
            float4 f01 = (r0 < n) ? *(const float4*)&feat[r0 * IN_F + k0 + 4] : z;
            float4 f10 = (r1 < n) ? *(const float4*)&feat[r1 * IN_F + k0] : z;
            float4 f11 = (r1 < n) ? *(const float4*)&feat[r1 * IN_F + k0 + 4] : z;
            union { short8 s; unsigned short u[8]; } ua, ub;
            ua.u[0] = f2bf(f00.x); ua.u[1] = f2bf(f00.y); ua.u[2] = f2bf(f00.z); ua.u[3] = f2bf(f00.w);
            ua.u[4] = f2bf(f01.x); ua.u[5] = f2bf(f01.y); ua.u[6] = f2bf(f01.z); ua.u[7] = f2bf(f01.w);
            ub.u[0] = f2bf(f10.x); ub.u[1] = f2bf(f10.y); ub.u[2] = f2bf(f10.z); ub.u[3] = f2bf(f10.w);
            ub.u[4] = f2bf(f11.x); ub.u[5] = f2bf(f11.y); ub.u[6] = f2bf(f11.z); ub.u[7] = f2bf(f11.w);
            a0 = ua.s; a1 = ub.s;
        } else {
            int ka = k0 - 128;
            short8 z = {0,0,0,0,0,0,0,0};
            a0 = (r0 < n) ? *(const short8*)&agg_bf[r0 * IN_F + ka] : z;
            a1 = (r1 < n) ? *(const short8*)&agg_bf[r1 * IN_F + ka] : z;
        }
#pragma unroll
        for (int nt = 0; nt < 8; ++nt) {
            short8 b = *(const short8*)&BL[(nt * 16 + lq) * BK_PAD + k0];
            acc0[nt] = __builtin_amdgcn_mfma_f32_16x16x32_bf16(a0, b, acc0[nt], 0, 0, 0);
            acc1[nt] = __builtin_amdgcn_mfma_f32_16x16x32_bf16(a1, b, acc1[nt], 0, 0, 0);
        }
    }

#pragma unroll
    for (int nt = 0; nt < 8; ++nt) {
        int col = nt * 16 + lq;
        float bb = bias[col];
#pragma unroll
        for (int r = 0; r < 4; ++r) {
            int row = rowbase + quad * 4 + r;
            if (row < n) out[row * OUT_F + col] = acc0[nt][r] + bb;
            int row2 = row + 16;
            if (row2 < n) out[row2 * OUT_F + col] = acc1[nt][r] + bb;
        }
    }
}

// ---------------------------------------------------------------------------
extern "C" void kernel_launch(void* const* d_in, const int* in_sizes, int n_in,
                              void* d_out, int out_size, void* d_ws, size_t ws_size,
                              hipStream_t stream) {
    const float* feat    = (const float*)d_in[0];
    const float* vals    = (const float*)d_in[1];
    const int*   idxs    = (const int*)d_in[2];
    const int*   src     = (const int*)d_in[3];
    const int*   dst     = (const int*)d_in[4];
    const float* W_self  = (const float*)d_in[5];
    const float* b_self  = (const float*)d_in[6];
    const float* W_neigh = (const float*)d_in[7];
    float*       out     = (float*)d_out;

    const int n = N_NODES;
    const int E = N_EDGES;

    // Workspace: [deg N][cursor N][off N+4][esrc E][packed N*32 u32][agg_bf N*128 u16]
    char* p = (char*)d_ws;
    int*            deg    = (int*)p;       p += (size_t)n * sizeof(int);
    int*            cursor = (int*)p;       p += (size_t)n * sizeof(int);
    int*            off    = (int*)p;       p += (size_t)(n + 4) * sizeof(int);
    int*            esrc   = (int*)p;       p += (size_t)E * sizeof(int);
    unsigned*       packed = (unsigned*)p;  p += (size_t)n * TOPK * sizeof(unsigned);
    unsigned short* agg_bf = (unsigned short*)p;

    hipMemsetAsync(d_ws, 0, 2ull * n * sizeof(int), stream);

    deg_mask_pack_kernel<<<(E + 255) / 256, 256, 0, stream>>>(dst, deg, vals, idxs, packed, E, n);
    scan_kernel<<<1, 1024, 0, stream>>>(deg, off, n);
    csr_scatter_kernel<<<(E + 255) / 256, 256, 0, stream>>>(src, dst, off, cursor, esrc, E);
    agg_packed_kernel<<<n, 64, 0, stream>>>(off, esrc, (const uint2*)packed, agg_bf, n);
    fused_gemm_kernel<<<(n + 127) / 128, 256, 0, stream>>>(feat, agg_bf, W_self, W_neigh, b_self, out, n);
}

// Round 6
// 426.116 us; speedup vs baseline: 1.0452x; 1.0452x over previous
//
#include <hip/hip_runtime.h>
#include <hip/hip_bf16.h>

#define N_NODES 50000
#define N_EDGES 800000
#define IN_F 128
#define OUT_F 128
#define TOPK 32

typedef __attribute__((ext_vector_type(8))) short short8;
typedef __attribute__((ext_vector_type(4))) float f32x4;

static __device__ inline unsigned short f2bf(float x) {
    __hip_bfloat16 h = __float2bfloat16(x);
    return *reinterpret_cast<unsigned short*>(&h);
}

// ---------------------------------------------------------------------------
// Kernel 1: fused in-degree count + dedup mask + payload pack.
// packed[node][k] = (bf16(val if slot wins else 0) << 16) | idx
// ---------------------------------------------------------------------------
__global__ void deg_mask_pack_kernel(const int* __restrict__ dst, int* __restrict__ deg,
                                     const float* __restrict__ vals,
                                     const int* __restrict__ topk_idx,
                                     unsigned* __restrict__ packed, int E, int n) {
    int t = blockIdx.x * blockDim.x + threadIdx.x;
    if (t < E) atomicAdd(&deg[dst[t]], 1);
    if (t < n) {
        int idx[TOPK];
        float v[TOPK];
#pragma unroll
        for (int k = 0; k < TOPK; k += 4) {
            *(int4*)&idx[k] = *(const int4*)&topk_idx[t * TOPK + k];
            *(float4*)&v[k] = *(const float4*)&vals[t * TOPK + k];
        }
        unsigned o[TOPK];
#pragma unroll
        for (int k = 0; k < TOPK; ++k) {
            bool win = true;
            for (int j = k + 1; j < TOPK; ++j)
                if (idx[j] == idx[k]) { win = false; break; }
            float vv = win ? v[k] : 0.f;
            o[k] = ((unsigned)f2bf(vv) << 16) | (unsigned)(idx[k] & 0xffff);
        }
#pragma unroll
        for (int k = 0; k < TOPK; k += 4)
            *(uint4*)&packed[t * TOPK + k] = *(const uint4*)&o[k];
    }
}

// ---------------------------------------------------------------------------
// Kernel 2: single-block exclusive scan of deg -> off[0..n]
// ---------------------------------------------------------------------------
__global__ __launch_bounds__(1024) void scan_kernel(const int* __restrict__ deg,
                                                    int* __restrict__ off, int n) {
    __shared__ int partial[1024];
    int t = threadIdx.x;
    int chunk = (n + 1023) / 1024;
    int start = t * chunk;
    int end = min(start + chunk, n);
    int s = 0;
    for (int i = start; i < end; ++i) s += deg[i];
    partial[t] = s;
    __syncthreads();
    for (int d = 1; d < 1024; d <<= 1) {
        int v = (t >= d) ? partial[t - d] : 0;
        __syncthreads();
        partial[t] += v;
        __syncthreads();
    }
    int run = (t > 0) ? partial[t - 1] : 0;
    for (int i = start; i < end; ++i) { off[i] = run; run += deg[i]; }
    if (t == 1023) off[n] = run;
}

// ---------------------------------------------------------------------------
// Kernel 3: CSR scatter — esrc[off[d] + cursor[d]++] = src[e]
// ---------------------------------------------------------------------------
__global__ void csr_scatter_kernel(const int* __restrict__ src, const int* __restrict__ dst,
                                   const int* __restrict__ off, int* __restrict__ cursor,
                                   int* __restrict__ esrc, int E) {
    int e = blockIdx.x * blockDim.x + threadIdx.x;
    if (e >= E) return;
    int d = dst[e];
    int pos = off[d] + atomicAdd(&cursor[d], 1);
    esrc[pos] = src[e];
}

// ---------------------------------------------------------------------------
// Kernel 4: aggregation over packed payload.
// 256-thr blocks = 4 waves, one dst node PER WAVE (wave-private LDS acc,
// no __syncthreads) -> 2x resident waves/CU vs 64-thr blocks.
// 32 lanes per edge (lane k owns slot k), 4 edges per iteration via
// half-waves, 1-deep software pipeline: loads for iter j+4 issue before
// the atomics of iter j, breaking the esrc->packed->atomic serial chain.
// Branchless tail: clamped edge index + zero multiplier.
// ---------------------------------------------------------------------------
__global__ __launch_bounds__(256) void agg_packed_kernel(
    const int* __restrict__ off, const int* __restrict__ esrc,
    const unsigned* __restrict__ packed,  // [N][32]
    unsigned short* __restrict__ agg_bf, int n) {
    __shared__ float acc[4][IN_F];
    int wv = threadIdx.x >> 6;
    int l = threadIdx.x & 63;
    int d = blockIdx.x * 4 + wv;
    if (d >= n) return;
    float* a = acc[wv];
    a[l] = 0.f;
    a[l + 64] = 0.f;

    int b = off[d], e = off[d + 1];
    int k = l & 31, half = l >> 5;

    unsigned p0, p1;
    float m0, m1;
#define LOAD4(J, Q0, Q1, W0, W1)                         \
    {                                                    \
        int ja = (J) + half;                             \
        int jb = (J) + 2 + half;                         \
        int ia = min(ja, e - 1), ib = min(jb, e - 1);    \
        int s0 = esrc[ia], s1 = esrc[ib];                \
        Q0 = packed[s0 * 32 + k];                        \
        Q1 = packed[s1 * 32 + k];                        \
        W0 = (ja < e) ? 1.f : 0.f;                       \
        W1 = (jb < e) ? 1.f : 0.f;                       \
    }

    if (b < e) {
        LOAD4(b, p0, p1, m0, m1);
        for (int j = b; j < e; j += 4) {
            unsigned q0 = 0, q1 = 0;
            float w0 = 0.f, w1 = 0.f;
            int jn = j + 4;
            if (jn < e) LOAD4(jn, q0, q1, w0, w1);
            float v0 = __uint_as_float(p0 & 0xffff0000u) * m0;
            float v1 = __uint_as_float(p1 & 0xffff0000u) * m1;
            atomicAdd(&a[p0 & 127], v0);
            atomicAdd(&a[p1 & 127], v1);
            p0 = q0; p1 = q1; m0 = w0; m1 = w1;
        }
    }
#undef LOAD4

    float inv = 1.0f / (float)max(e - b, 1);
    __hip_bfloat162 h;
    h.x = __float2bfloat16(a[2 * l] * inv);
    h.y = __float2bfloat16(a[2 * l + 1] * inv);
    *(__hip_bfloat162*)&agg_bf[d * IN_F + 2 * l] = h;
}

// ---------------------------------------------------------------------------
// Kernel 5: fused MFMA GEMM:  out = [feat | agg] @ [Ws ; Wn] + b
// M=50000, N=128, K=256, bf16 MFMA 16x16x32.
// ---------------------------------------------------------------------------
#define BK_PAD 264
__global__ __launch_bounds__(256, 2) void fused_gemm_kernel(
    const float* __restrict__ feat, const unsigned short* __restrict__ agg_bf,
    const float* __restrict__ Ws, const float* __restrict__ Wn,
    const float* __restrict__ bias, float* __restrict__ out, int n) {
    __shared__ unsigned short BL[OUT_F * BK_PAD];  // 67.5 KB

    int t = threadIdx.x;
    {
        int col = t & 127;
        int khalf = t >> 7;
        const float* W = khalf ? Wn : Ws;
        unsigned short* dstp = &BL[col * BK_PAD + khalf * 128];
#pragma unroll 4
        for (int kk = 0; kk < 128; kk += 2) {
            float w0 = W[kk * OUT_F + col];
            float w1 = W[(kk + 1) * OUT_F + col];
            unsigned v = (unsigned)f2bf(w0) | ((unsigned)f2bf(w1) << 16);
            *(unsigned*)&dstp[kk] = v;
        }
    }
    __syncthreads();

    int wave = t >> 6;
    int lane = t & 63;
    int quad = lane >> 4;
    int lq = lane & 15;
    int rowbase = blockIdx.x * 128 + wave * 32;
    int r0 = rowbase + lq;
    int r1 = rowbase + 16 + lq;

    f32x4 acc0[8], acc1[8];
#pragma unroll
    for (int i = 0; i < 8; ++i) { acc0[i] = (f32x4){0,0,0,0}; acc1[i] = (f32x4){0,0,0,0}; }

#pragma unroll
    for (int ks = 0; ks < 8; ++ks) {
        int k0 = ks * 32 + quad * 8;
        short8 a0, a1;
        if (ks < 4) {
            float4 z = {0.f, 0.f, 0.f, 0.f};
            float4 f00 = (r0 < n) ? *(const float4*)&feat[r0 * IN_F + k0] : z;
            float4 f01 = (r0 < n) ? *(const float4*)&feat[r0 * IN_F + k0 + 4] : z;
            float4 f10 = (r1 < n) ? *(const float4*)&feat[r1 * IN_F + k0] : z;
            float4 f11 = (r1 < n) ? *(const float4*)&feat[r1 * IN_F + k0 + 4] : z;
            union { short8 s; unsigned short u[8]; } ua, ub;
            ua.u[0] = f2bf(f00.x); ua.u[1] = f2bf(f00.y); ua.u[2] = f2bf(f00.z); ua.u[3] = f2bf(f00.w);
            ua.u[4] = f2bf(f01.x); ua.u[5] = f2bf(f01.y); ua.u[6] = f2bf(f01.z); ua.u[7] = f2bf(f01.w);
            ub.u[0] = f2bf(f10.x); ub.u[1] = f2bf(f10.y); ub.u[2] = f2bf(f10.z); ub.u[3] = f2bf(f10.w);
            ub.u[4] = f2bf(f11.x); ub.u[5] = f2bf(f11.y); ub.u[6] = f2bf(f11.z); ub.u[7] = f2bf(f11.w);
            a0 = ua.s; a1 = ub.s;
        } else {
            int ka = k0 - 128;
            short8 z = {0,0,0,0,0,0,0,0};
            a0 = (r0 < n) ? *(const short8*)&agg_bf[r0 * IN_F + ka] : z;
            a1 = (r1 < n) ? *(const short8*)&agg_bf[r1 * IN_F + ka] : z;
        }
#pragma unroll
        for (int nt = 0; nt < 8; ++nt) {
            short8 b = *(const short8*)&BL[(nt * 16 + lq) * BK_PAD + k0];
            acc0[nt] = __builtin_amdgcn_mfma_f32_16x16x32_bf16(a0, b, acc0[nt], 0, 0, 0);
            acc1[nt] = __builtin_amdgcn_mfma_f32_16x16x32_bf16(a1, b, acc1[nt], 0, 0, 0);
        }
    }

#pragma unroll
    for (int nt = 0; nt < 8; ++nt) {
        int col = nt * 16 + lq;
        float bb = bias[col];
#pragma unroll
        for (int r = 0; r < 4; ++r) {
            int row = rowbase + quad * 4 + r;
            if (row < n) out[row * OUT_F + col] = acc0[nt][r] + bb;
            int row2 = row + 16;
            if (row2 < n) out[row2 * OUT_F + col] = acc1[nt][r] + bb;
        }
    }
}

// ---------------------------------------------------------------------------
extern "C" void kernel_launch(void* const* d_in, const int* in_sizes, int n_in,
                              void* d_out, int out_size, void* d_ws, size_t ws_size,
                              hipStream_t stream) {
    const float* feat    = (const float*)d_in[0];
    const float* vals    = (const float*)d_in[1];
    const int*   idxs    = (const int*)d_in[2];
    const int*   src     = (const int*)d_in[3];
    const int*   dst     = (const int*)d_in[4];
    const float* W_self  = (const float*)d_in[5];
    const float* b_self  = (const float*)d_in[6];
    const float* W_neigh = (const float*)d_in[7];
    float*       out     = (float*)d_out;

    const int n = N_NODES;
    const int E = N_EDGES;

    // Workspace: [deg N][cursor N][off N+4][esrc E][packed N*32 u32][agg_bf N*128 u16]
    char* p = (char*)d_ws;
    int*            deg    = (int*)p;       p += (size_t)n * sizeof(int);
    int*            cursor = (int*)p;       p += (size_t)n * sizeof(int);
    int*            off    = (int*)p;       p += (size_t)(n + 4) * sizeof(int);
    int*            esrc   = (int*)p;       p += (size_t)E * sizeof(int);
    unsigned*       packed = (unsigned*)p;  p += (size_t)n * TOPK * sizeof(unsigned);
    unsigned short* agg_bf = (unsigned short*)p;

    hipMemsetAsync(d_ws, 0, 2ull * n * sizeof(int), stream);

    deg_mask_pack_kernel<<<(E + 255) / 256, 256, 0, stream>>>(dst, deg, vals, idxs, packed, E, n);
    scan_kernel<<<1, 1024, 0, stream>>>(deg, off, n);
    csr_scatter_kernel<<<(E + 255) / 256, 256, 0, stream>>>(src, dst, off, cursor, esrc, E);
    agg_packed_kernel<<<(n + 3) / 4, 256, 0, stream>>>(off, esrc, packed, agg_bf, n);
    fused_gemm_kernel<<<(n + 127) / 128, 256, 0, stream>>>(feat, agg_bf, W_self, W_neigh, b_self, out, n);
}

// Round 7
// 350.860 us; speedup vs baseline: 1.2694x; 1.2145x over previous
//
#include <hip/hip_runtime.h>
#include <hip/hip_bf16.h>

#define N_NODES 50000
#define N_EDGES 800000
#define IN_F 128
#define OUT_F 128
#define TOPK 32

typedef __attribute__((ext_vector_type(8))) short short8;
typedef __attribute__((ext_vector_type(4))) float f32x4;

static __device__ inline unsigned short f2bf(float x) {
    __hip_bfloat16 h = __float2bfloat16(x);
    return *reinterpret_cast<unsigned short*>(&h);
}

// ---------------------------------------------------------------------------
// Kernel 1: fused in-degree count (capturing per-edge rank) + dedup mask +
// payload pack: packed[node][k] = (bf16(val if slot wins else 0) << 16) | idx
// ---------------------------------------------------------------------------
__global__ void deg_mask_pack_kernel(const int* __restrict__ dst, int* __restrict__ deg,
                                     int* __restrict__ rank,
                                     const float* __restrict__ vals,
                                     const int* __restrict__ topk_idx,
                                     unsigned* __restrict__ packed, int E, int n) {
    int t = blockIdx.x * blockDim.x + threadIdx.x;
    if (t < E) rank[t] = atomicAdd(&deg[dst[t]], 1);
    if (t < n) {
        int idx[TOPK];
        float v[TOPK];
#pragma unroll
        for (int k = 0; k < TOPK; k += 4) {
            *(int4*)&idx[k] = *(const int4*)&topk_idx[t * TOPK + k];
            *(float4*)&v[k] = *(const float4*)&vals[t * TOPK + k];
        }
        unsigned o[TOPK];
#pragma unroll
        for (int k = 0; k < TOPK; ++k) {
            bool win = true;
            for (int j = k + 1; j < TOPK; ++j)
                if (idx[j] == idx[k]) { win = false; break; }
            float vv = win ? v[k] : 0.f;
            o[k] = ((unsigned)f2bf(vv) << 16) | (unsigned)(idx[k] & 0xffff);
        }
#pragma unroll
        for (int k = 0; k < TOPK; k += 4)
            *(uint4*)&packed[t * TOPK + k] = *(const uint4*)&o[k];
    }
}

// ---------------------------------------------------------------------------
// Scan (3-phase, multi-block): A) per-block sums  B) scan of block sums
// C) per-block scan + global offset.  Replaces the serial 1-block scan.
// ---------------------------------------------------------------------------
__global__ __launch_bounds__(256) void scan_phaseA(const int* __restrict__ deg,
                                                   int* __restrict__ bsum, int n) {
    __shared__ int red[256];
    int t = threadIdx.x, i = blockIdx.x * 256 + t;
    red[t] = (i < n) ? deg[i] : 0;
    __syncthreads();
    for (int s = 128; s > 0; s >>= 1) {
        if (t < s) red[t] += red[t + s];
        __syncthreads();
    }
    if (t == 0) bsum[blockIdx.x] = red[0];
}

__global__ __launch_bounds__(256) void scan_phaseB(const int* __restrict__ bsum,
                                                   int* __restrict__ boff,
                                                   int* __restrict__ off_total,
                                                   int nb) {
    __shared__ int sc[256];
    int t = threadIdx.x;
    int v = (t < nb) ? bsum[t] : 0;
    sc[t] = v;
    __syncthreads();
    for (int s = 1; s < 256; s <<= 1) {
        int add = (t >= s) ? sc[t - s] : 0;
        __syncthreads();
        sc[t] += add;
        __syncthreads();
    }
    boff[t] = sc[t] - v;  // exclusive
    if (t == nb - 1) off_total[0] = sc[t];
}

__global__ __launch_bounds__(256) void scan_phaseC(const int* __restrict__ deg,
                                                   const int* __restrict__ boff,
                                                   int* __restrict__ off, int n) {
    __shared__ int sc[256];
    int t = threadIdx.x, i = blockIdx.x * 256 + t;
    int v = (i < n) ? deg[i] : 0;
    sc[t] = v;
    __syncthreads();
    for (int s = 1; s < 256; s <<= 1) {
        int add = (t >= s) ? sc[t - s] : 0;
        __syncthreads();
        sc[t] += add;
        __syncthreads();
    }
    if (i < n) off[i] = sc[t] - v + boff[blockIdx.x];
}

// ---------------------------------------------------------------------------
// Kernel 3: CSR scatter — no atomics (rank precomputed in deg kernel).
// ---------------------------------------------------------------------------
__global__ void csr_scatter_kernel(const int* __restrict__ src, const int* __restrict__ dst,
                                   const int* __restrict__ off, const int* __restrict__ rank,
                                   int* __restrict__ esrc, int E) {
    int e = blockIdx.x * blockDim.x + threadIdx.x;
    if (e >= E) return;
    esrc[off[dst[e]] + rank[e]] = src[e];
}

// ---------------------------------------------------------------------------
// Kernel 4: aggregation. One wave per dst node, 4 waves/block.
// KEY FIX vs r5/r6: esrc for up to 64 edges is batch-loaded in ONE coalesced
// load into a register; per-edge src ids come from __shfl (register-only).
// The packed gathers are then fully independent -> 4 issued back-to-back per
// unrolled step, pipelining across steps (8+ loads in flight per wave).
// ---------------------------------------------------------------------------
__global__ __launch_bounds__(256) void agg_packed_kernel(
    const int* __restrict__ off, const int* __restrict__ esrc,
    const unsigned* __restrict__ packed,  // [N][32]
    unsigned short* __restrict__ agg_bf, int n) {
    __shared__ float acc[4][IN_F];
    int wv = threadIdx.x >> 6;
    int l = threadIdx.x & 63;
    int d = blockIdx.x * 4 + wv;
    if (d >= n) return;
    float* a = acc[wv];
    a[l] = 0.f;
    a[l + 64] = 0.f;

    int b = off[d], e = off[d + 1];
    int k = l & 31, half = l >> 5;

    for (int base = b; base < e; base += 64) {
        int cnt = e - base;
        if (cnt > 64) cnt = 64;
        // one coalesced load covers up to 64 edges' src ids
        int sv = esrc[min(base + l, e - 1)];
#pragma unroll 1
        for (int i = 0; i < cnt; i += 8) {
            unsigned p[4];
            float m[4];
#pragma unroll
            for (int u = 0; u < 4; ++u) {
                int ii = i + 2 * u + half;
                m[u] = (ii < cnt) ? 1.f : 0.f;
                int s = __shfl(sv, min(ii, cnt - 1));
                p[u] = packed[s * 32 + k];
            }
#pragma unroll
            for (int u = 0; u < 4; ++u) {
                float v = __uint_as_float(p[u] & 0xffff0000u) * m[u];
                atomicAdd(&a[p[u] & 127], v);
            }
        }
    }

    float inv = 1.0f / (float)max(e - b, 1);
    __hip_bfloat162 h;
    h.x = __float2bfloat16(a[2 * l] * inv);
    h.y = __float2bfloat16(a[2 * l + 1] * inv);
    *(__hip_bfloat162*)&agg_bf[d * IN_F + 2 * l] = h;
}

// ---------------------------------------------------------------------------
// Kernel 5: fused MFMA GEMM:  out = [feat | agg] @ [Ws ; Wn] + b
// M=50000, N=128, K=256, bf16 MFMA 16x16x32. (unchanged)
// ---------------------------------------------------------------------------
#define BK_PAD 264
__global__ __launch_bounds__(256, 2) void fused_gemm_kernel(
    const float* __restrict__ feat, const unsigned short* __restrict__ agg_bf,
    const float* __restrict__ Ws, const float* __restrict__ Wn,
    const float* __restrict__ bias, float* __restrict__ out, int n) {
    __shared__ unsigned short BL[OUT_F * BK_PAD];  // 67.5 KB

    int t = threadIdx.x;
    {
        int col = t & 127;
        int khalf = t >> 7;
        const float* W = khalf ? Wn : Ws;
        unsigned short* dstp = &BL[col * BK_PAD + khalf * 128];
#pragma unroll 4
        for (int kk = 0; kk < 128; kk += 2) {
            float w0 = W[kk * OUT_F + col];
            float w1 = W[(kk + 1) * OUT_F + col];
            unsigned v = (unsigned)f2bf(w0) | ((unsigned)f2bf(w1) << 16);
            *(unsigned*)&dstp[kk] = v;
        }
    }
    __syncthreads();

    int wave = t >> 6;
    int lane = t & 63;
    int quad = lane >> 4;
    int lq = lane & 15;
    int rowbase = blockIdx.x * 128 + wave * 32;
    int r0 = rowbase + lq;
    int r1 = rowbase + 16 + lq;

    f32x4 acc0[8], acc1[8];
#pragma unroll
    for (int i = 0; i < 8; ++i) { acc0[i] = (f32x4){0,0,0,0}; acc1[i] = (f32x4){0,0,0,0}; }

#pragma unroll
    for (int ks = 0; ks < 8; ++ks) {
        int k0 = ks * 32 + quad * 8;
        short8 a0, a1;
        if (ks < 4) {
            float4 z = {0.f, 0.f, 0.f, 0.f};
            float4 f00 = (r0 < n) ? *(const float4*)&feat[r0 * IN_F + k0] : z;
            float4 f01 = (r0 < n) ? *(const float4*)&feat[r0 * IN_F + k0 + 4] : z;
            float4 f10 = (r1 < n) ? *(const float4*)&feat[r1 * IN_F + k0] : z;
            float4 f11 = (r1 < n) ? *(const float4*)&feat[r1 * IN_F + k0 + 4] : z;
            union { short8 s; unsigned short u[8]; } ua, ub;
            ua.u[0] = f2bf(f00.x); ua.u[1] = f2bf(f00.y); ua.u[2] = f2bf(f00.z); ua.u[3] = f2bf(f00.w);
            ua.u[4] = f2bf(f01.x); ua.u[5] = f2bf(f01.y); ua.u[6] = f2bf(f01.z); ua.u[7] = f2bf(f01.w);
            ub.u[0] = f2bf(f10.x); ub.u[1] = f2bf(f10.y); ub.u[2] = f2bf(f10.z); ub.u[3] = f2bf(f10.w);
            ub.u[4] = f2bf(f11.x); ub.u[5] = f2bf(f11.y); ub.u[6] = f2bf(f11.z); ub.u[7] = f2bf(f11.w);
            a0 = ua.s; a1 = ub.s;
        } else {
            int ka = k0 - 128;
            short8 z = {0,0,0,0,0,0,0,0};
            a0 = (r0 < n) ? *(const short8*)&agg_bf[r0 * IN_F + ka] : z;
            a1 = (r1 < n) ? *(const short8*)&agg_bf[r1 * IN_F + ka] : z;
        }
#pragma unroll
        for (int nt = 0; nt < 8; ++nt) {
            short8 b = *(const short8*)&BL[(nt * 16 + lq) * BK_PAD + k0];
            acc0[nt] = __builtin_amdgcn_mfma_f32_16x16x32_bf16(a0, b, acc0[nt], 0, 0, 0);
            acc1[nt] = __builtin_amdgcn_mfma_f32_16x16x32_bf16(a1, b, acc1[nt], 0, 0, 0);
        }
    }

#pragma unroll
    for (int nt = 0; nt < 8; ++nt) {
        int col = nt * 16 + lq;
        float bb = bias[col];
#pragma unroll
        for (int r = 0; r < 4; ++r) {
            int row = rowbase + quad * 4 + r;
            if (row < n) out[row * OUT_F + col] = acc0[nt][r] + bb;
            int row2 = row + 16;
            if (row2 < n) out[row2 * OUT_F + col] = acc1[nt][r] + bb;
        }
    }
}

// ---------------------------------------------------------------------------
extern "C" void kernel_launch(void* const* d_in, const int* in_sizes, int n_in,
                              void* d_out, int out_size, void* d_ws, size_t ws_size,
                              hipStream_t stream) {
    const float* feat    = (const float*)d_in[0];
    const float* vals    = (const float*)d_in[1];
    const int*   idxs    = (const int*)d_in[2];
    const int*   src     = (const int*)d_in[3];
    const int*   dst     = (const int*)d_in[4];
    const float* W_self  = (const float*)d_in[5];
    const float* b_self  = (const float*)d_in[6];
    const float* W_neigh = (const float*)d_in[7];
    float*       out     = (float*)d_out;

    const int n = N_NODES;
    const int E = N_EDGES;
    const int nb = (n + 255) / 256;  // 196 scan blocks

    // Workspace: [deg N][off N+4][rank E][esrc E][packed N*32][agg_bf N*128 u16][bsum 256][boff 256]
    char* p = (char*)d_ws;
    int*            deg    = (int*)p;       p += (size_t)n * sizeof(int);
    int*            off    = (int*)p;       p += (size_t)(n + 4) * sizeof(int);
    int*            rank   = (int*)p;       p += (size_t)E * sizeof(int);
    int*            esrc   = (int*)p;       p += (size_t)E * sizeof(int);
    unsigned*       packed = (unsigned*)p;  p += (size_t)n * TOPK * sizeof(unsigned);
    unsigned short* agg_bf = (unsigned short*)p; p += (size_t)n * IN_F * sizeof(unsigned short);
    int*            bsum   = (int*)p;       p += 256 * sizeof(int);
    int*            boff   = (int*)p;

    hipMemsetAsync(deg, 0, (size_t)n * sizeof(int), stream);

    deg_mask_pack_kernel<<<(E + 255) / 256, 256, 0, stream>>>(dst, deg, rank, vals, idxs, packed, E, n);
    scan_phaseA<<<nb, 256, 0, stream>>>(deg, bsum, n);
    scan_phaseB<<<1, 256, 0, stream>>>(bsum, boff, &off[n], nb);
    scan_phaseC<<<nb, 256, 0, stream>>>(deg, boff, off, n);
    csr_scatter_kernel<<<(E + 255) / 256, 256, 0, stream>>>(src, dst, off, rank, esrc, E);
    agg_packed_kernel<<<(n + 3) / 4, 256, 0, stream>>>(off, esrc, packed, agg_bf, n);
    fused_gemm_kernel<<<(n + 127) / 128, 256, 0, stream>>>(feat, agg_bf, W_self, W_neigh, b_self, out, n);
}